// Round 7
// baseline (134.773 us; speedup 1.0000x reference)
//
#include <hip/hip_runtime.h>

#define BATCH 65536
#define DIM 512
#define NCLS 100
#define ALPHA 0.5f

#define CAP 1024            // per-class slot capacity (max count ~780 for B=65536,C=100)
#define SORT_RPB 256        // rows per block in sort_kernel (1 row/thread)
#define SORT_THREADS 256
#define CHUNKS 32           // blocks per class in delta_kernel
#define CBLOCK 256          // threads per block (4 waves)
#define SLOTS (CHUNKS * (CBLOCK / 64))   // 128 wave-slots per class
#define KMAX 8              // max iterations per wave: ceil(CAP/SLOTS)

// workspace layout
#define WS_COUNTS_OFF 0
#define WS_ORDER_OFF  512
#define WS_AUX_OFF    (512 + NCLS * CAP * 4)          // part (6.5MB) or sumf (200KB)
#define WS_PART_BYTES (CHUNKS * NCLS * DIM * 4)

typedef float f4v __attribute__((ext_vector_type(4)));

// ---------------------------------------------------------------------------
// Kernel A: fused label-extract + counting-sort with LDS histogram.
// Label via exact dot-product: label[b] = sum_c onehot[b][c] * c.
// Only 100 global atomics per block (base-offset claim).
// ---------------------------------------------------------------------------
__global__ void __launch_bounds__(SORT_THREADS)
sort_kernel(const float* __restrict__ onehot,
            int* __restrict__ counts,      // [NCLS], pre-zeroed
            int* __restrict__ order) {     // [NCLS][CAP]
    __shared__ int lhist[NCLS];
    __shared__ int lbase[NCLS];
    __shared__ short llab[SORT_RPB];
    __shared__ short lrank[SORT_RPB];

    const int t = threadIdx.x;
    const int r0 = blockIdx.x * SORT_RPB;

    for (int c = t; c < NCLS; c += SORT_THREADS) lhist[c] = 0;
    __syncthreads();

    const float4* oh4 = reinterpret_cast<const float4*>(onehot);
    {
        const int b = r0 + t;
        float lab = 0.0f;
#pragma unroll
        for (int j = 0; j < NCLS / 4; ++j) {
            const float4 v = oh4[b * (NCLS / 4) + j];
            lab += v.x * (float)(4 * j)
                 + v.y * (float)(4 * j + 1)
                 + v.z * (float)(4 * j + 2)
                 + v.w * (float)(4 * j + 3);
        }
        const int c = (int)(lab + 0.5f);
        llab[t] = (short)c;
        lrank[t] = (short)atomicAdd(&lhist[c], 1);
    }
    __syncthreads();

    for (int c = t; c < NCLS; c += SORT_THREADS)
        lbase[c] = atomicAdd(&counts[c], lhist[c]);
    __syncthreads();

    {
        const int c = llab[t];
        order[c * CAP + lbase[c] + lrank[t]] = r0 + t;
    }
}

// ---------------------------------------------------------------------------
// Kernel B: fused squared-distance + per-class feature-sum.
// grid = (CHUNKS, NCLS), block = 256 (4 waves); each wave handles rows of ONE
// class; lane owns dims [lane*8, lane*8+8).
// This round: (1) prefetch ALL ord indices per wave up front (removes the
// serial ord->feature dependent chain), (2) explicit load-phase/compute-phase
// with compile-time-indexed register arrays (no scratch), (3) nontemporal
// feature loads (134MB single-pass stream; keep L2 for order/centers/partials).
// NO device-scope fences (round-5 lesson: per-block __threadfence = L2 flush).
// ---------------------------------------------------------------------------
__global__ void __launch_bounds__(CBLOCK)
delta_kernel(const float* __restrict__ features,
             const float* __restrict__ centers,
             const int* __restrict__ order,
             const int* __restrict__ counts,
             float* __restrict__ aux,       // part [CHUNKS][NCLS][DIM] or sumf [NCLS][DIM]
             float* __restrict__ result,    // [BATCH], each row written once
             const int use_part) {
    __shared__ float red[4][DIM];          // 8 KB

    const int c = blockIdx.y;
    const int cnt = counts[c];
    const int lane = threadIdx.x & 63;
    const int wave = threadIdx.x >> 6;
    const int slot = blockIdx.x * (CBLOCK / 64) + wave;   // 0..SLOTS-1
    const int d = lane * 8;

    const f4v c0 = *reinterpret_cast<const f4v*>(&centers[c * DIM + d]);
    const f4v c1 = *reinterpret_cast<const f4v*>(&centers[c * DIM + d + 4]);
    f4v sA = (f4v)(0.0f);
    f4v sB = (f4v)(0.0f);

    // ---- index prefetch: always in-bounds of the order buffer (slot+7*128<1024)
    const int* ord = &order[c * CAP];
    int idx[KMAX];
#pragma unroll
    for (int k = 0; k < KMAX; ++k) idx[k] = ord[slot + k * SLOTS];

    // ---- load phase: issue all feature loads (nontemporal, streamed once)
    f4v F0[KMAX], F1[KMAX];
#pragma unroll
    for (int k = 0; k < KMAX; ++k) {
        if (slot + k * SLOTS < cnt) {
            const float* p = &features[(long)idx[k] * DIM + d];
            F0[k] = __builtin_nontemporal_load(reinterpret_cast<const f4v*>(p));
            F1[k] = __builtin_nontemporal_load(reinterpret_cast<const f4v*>(p + 4));
        }
    }

    // ---- compute phase
#pragma unroll
    for (int k = 0; k < KMAX; ++k) {
        if (slot + k * SLOTS < cnt) {
            const f4v f0 = F0[k];
            const f4v f1 = F1[k];
            sA += f0;
            sB += f1;
            const f4v d0 = f0 - c0;
            const f4v d1 = f1 - c1;
            float sq = d0.x * d0.x + d0.y * d0.y + d0.z * d0.z + d0.w * d0.w
                     + d1.x * d1.x + d1.y * d1.y + d1.z * d1.z + d1.w * d1.w;
#pragma unroll
            for (int m = 32; m >= 1; m >>= 1) sq += __shfl_xor(sq, m);
            if (lane == 0) result[idx[k]] = sq;
        }
    }

    // ---- cross-wave reduction in LDS, then one streaming partial write per block
    float* r = &red[wave][d];
    r[0] = sA.x; r[1] = sA.y; r[2] = sA.z; r[3] = sA.w;
    r[4] = sB.x; r[5] = sB.y; r[6] = sB.z; r[7] = sB.w;
    __syncthreads();

    const int t = threadIdx.x;
    if (use_part) {
        float* dst = &aux[(blockIdx.x * NCLS + c) * DIM];
#pragma unroll
        for (int k = 0; k < DIM / CBLOCK; ++k) {
            const int dd = k * CBLOCK + t;
            dst[dd] = red[0][dd] + red[1][dd] + red[2][dd] + red[3][dd];
        }
    } else {
#pragma unroll
        for (int k = 0; k < DIM / CBLOCK; ++k) {
            const int dd = k * CBLOCK + t;
            const float s = red[0][dd] + red[1][dd] + red[2][dd] + red[3][dd];
            unsafeAtomicAdd(&aux[c * DIM + dd], s);
        }
    }
}

// ---------------------------------------------------------------------------
// Kernel C: new_centers = centers - ALPHA * (cnt*center - sumf) / (cnt + 1)
// ---------------------------------------------------------------------------
__global__ void finalize_kernel(const float* __restrict__ centers,
                                const float* __restrict__ aux,
                                const int* __restrict__ counts,
                                float* __restrict__ new_centers,
                                const int use_part) {
    const int idx = blockIdx.x * blockDim.x + threadIdx.x;
    if (idx >= NCLS * DIM) return;
    float s;
    if (use_part) {
        s = 0.0f;
#pragma unroll
        for (int k = 0; k < CHUNKS; ++k) s += aux[k * NCLS * DIM + idx];
    } else {
        s = aux[idx];
    }
    const int c = idx >> 9;                 // / DIM
    const float cntf = (float)counts[c];
    const float ctr = centers[idx];
    const float delta = (cntf * ctr - s) / (cntf + 1.0f);
    new_centers[idx] = ctr - ALPHA * delta;
}

extern "C" void kernel_launch(void* const* d_in, const int* in_sizes, int n_in,
                              void* d_out, int out_size, void* d_ws, size_t ws_size,
                              hipStream_t stream) {
    const float* features = (const float*)d_in[0];   // [65536, 512]
    const float* onehot   = (const float*)d_in[1];   // [65536, 100]
    const float* centers  = (const float*)d_in[2];   // [100, 512]

    float* result      = (float*)d_out;              // [65536]
    float* new_centers = (float*)d_out + BATCH;      // [100*512]

    char* ws = (char*)d_ws;
    int*   counts = (int*)(ws + WS_COUNTS_OFF);      // 128 ints
    int*   order  = (int*)(ws + WS_ORDER_OFF);       // NCLS*CAP ints
    float* aux    = (float*)(ws + WS_AUX_OFF);       // part or sumf

    const int use_part = (ws_size >= (size_t)WS_AUX_OFF + WS_PART_BYTES) ? 1 : 0;

    hipMemsetAsync(counts, 0, 128 * sizeof(int), stream);
    if (!use_part)
        hipMemsetAsync(aux, 0, NCLS * DIM * sizeof(float), stream);

    sort_kernel<<<BATCH / SORT_RPB, SORT_THREADS, 0, stream>>>(onehot, counts, order);

    dim3 grid(CHUNKS, NCLS);
    delta_kernel<<<grid, CBLOCK, 0, stream>>>(features, centers, order, counts, aux, result, use_part);

    finalize_kernel<<<(NCLS * DIM + 255) / 256, 256, 0, stream>>>(centers, aux, counts, new_centers, use_part);
}

// Round 9
// 47.195 us; speedup vs baseline: 2.8556x; 2.8556x over previous
//
#include <hip/hip_runtime.h>

#define BATCH 65536
#define DIM 512
#define NCLS 100
#define ALPHA 0.5f

#define CAP 1024            // per-class slot capacity (max count ~780 for B=65536,C=100)
#define SORT_RPB 512        // rows per block in sort_kernel
#define SORT_THREADS 256
#define CHUNKS 32           // blocks per class in delta_kernel
#define CBLOCK 256          // threads per block (4 waves)
#define SLOTS (CHUNKS * (CBLOCK / 64))   // 128 wave-slots per class

// workspace layout
#define WS_COUNTS_OFF 0
#define WS_ORDER_OFF  512
#define WS_AUX_OFF    (512 + NCLS * CAP * 4)          // part (6.5MB) or sumf (200KB)
#define WS_PART_BYTES (CHUNKS * NCLS * DIM * 4)

typedef float f4v __attribute__((ext_vector_type(4)));

// ---------------------------------------------------------------------------
// Kernel A: fused label-extract + counting-sort with LDS histogram.
// Label via exact dot-product: label[b] = sum_c onehot[b][c] * c — each row's
// label is computed by ITS OWN thread (no cross-thread publication; round-8
// lesson: conditional finder-publish into uninitialized LDS caused post-timing
// divergence via an LDS-OOB corruption cascade).
// Only 100 global atomics per block (base-offset claim).
// ---------------------------------------------------------------------------
__global__ void __launch_bounds__(SORT_THREADS)
sort_kernel(const float* __restrict__ onehot,
            int* __restrict__ counts,      // [NCLS], pre-zeroed
            int* __restrict__ order) {     // [NCLS][CAP]
    __shared__ int lhist[NCLS];
    __shared__ int lbase[NCLS];
    __shared__ short llab[SORT_RPB];
    __shared__ short lrank[SORT_RPB];

    const int t = threadIdx.x;
    const int r0 = blockIdx.x * SORT_RPB;

    for (int c = t; c < NCLS; c += SORT_THREADS) lhist[c] = 0;
    __syncthreads();

    const float4* oh4 = reinterpret_cast<const float4*>(onehot);
#pragma unroll
    for (int rr = 0; rr < SORT_RPB / SORT_THREADS; ++rr) {
        const int r = rr * SORT_THREADS + t;
        const int b = r0 + r;
        float lab = 0.0f;
#pragma unroll
        for (int j = 0; j < NCLS / 4; ++j) {
            const float4 v = oh4[b * (NCLS / 4) + j];
            lab += v.x * (float)(4 * j)
                 + v.y * (float)(4 * j + 1)
                 + v.z * (float)(4 * j + 2)
                 + v.w * (float)(4 * j + 3);
        }
        const int c = (int)(lab + 0.5f);
        llab[r] = (short)c;
        lrank[r] = (short)atomicAdd(&lhist[c], 1);
    }
    __syncthreads();

    for (int c = t; c < NCLS; c += SORT_THREADS)
        lbase[c] = atomicAdd(&counts[c], lhist[c]);
    __syncthreads();

#pragma unroll
    for (int rr = 0; rr < SORT_RPB / SORT_THREADS; ++rr) {
        const int r = rr * SORT_THREADS + t;
        const int c = llab[r];
        order[c * CAP + lbase[c] + lrank[r]] = r0 + r;
    }
}

// ---------------------------------------------------------------------------
// Kernel B: fused squared-distance + per-class feature-sum.
// grid = (CHUNKS, NCLS), block = 256 (4 waves), each wave handles rows of ONE
// class; lane owns dims [lane*8, lane*8+8). Register accumulation in the hot
// loop (unrolled x2 for MLP), LDS cross-wave reduce at block end, then ONE
// non-atomic 2KB streaming partial write per block (use_part mode).
// NO device-scope fences (round-5 lesson: per-block __threadfence = L2 flush,
// 5x regression). NO deep explicit prefetch (round-7 lesson: 212 VGPR -> 10%
// occupancy -> 2.5x regression).
// ---------------------------------------------------------------------------
__global__ void __launch_bounds__(CBLOCK)
delta_kernel(const float* __restrict__ features,
             const float* __restrict__ centers,
             const int* __restrict__ order,
             const int* __restrict__ counts,
             float* __restrict__ aux,       // part [CHUNKS][NCLS][DIM] or sumf [NCLS][DIM]
             float* __restrict__ result,    // [BATCH], each row written once
             const int use_part) {
    __shared__ float red[4][DIM];          // 8 KB

    const int c = blockIdx.y;
    const int cnt = counts[c];
    const int lane = threadIdx.x & 63;
    const int wave = threadIdx.x >> 6;
    const int slot = blockIdx.x * (CBLOCK / 64) + wave;   // 0..SLOTS-1
    const int d = lane * 8;

    const float4 c0 = *reinterpret_cast<const float4*>(&centers[c * DIM + d]);
    const float4 c1 = *reinterpret_cast<const float4*>(&centers[c * DIM + d + 4]);
    float4 sA = make_float4(0.f, 0.f, 0.f, 0.f);
    float4 sB = make_float4(0.f, 0.f, 0.f, 0.f);

    const int* ord = &order[c * CAP];
    int i = slot;
    for (; i + SLOTS < cnt; i += 2 * SLOTS) {
        const int b0 = ord[i];
        const int b1 = ord[i + SLOTS];
        const float4 f00 = *reinterpret_cast<const float4*>(&features[b0 * DIM + d]);
        const float4 f01 = *reinterpret_cast<const float4*>(&features[b0 * DIM + d + 4]);
        const float4 f10 = *reinterpret_cast<const float4*>(&features[b1 * DIM + d]);
        const float4 f11 = *reinterpret_cast<const float4*>(&features[b1 * DIM + d + 4]);

        sA.x += f00.x + f10.x; sA.y += f00.y + f10.y;
        sA.z += f00.z + f10.z; sA.w += f00.w + f10.w;
        sB.x += f01.x + f11.x; sB.y += f01.y + f11.y;
        sB.z += f01.z + f11.z; sB.w += f01.w + f11.w;

        float dx, dy, dz, dw;
        dx = f00.x - c0.x; dy = f00.y - c0.y; dz = f00.z - c0.z; dw = f00.w - c0.w;
        float sq0 = dx * dx + dy * dy + dz * dz + dw * dw;
        dx = f01.x - c1.x; dy = f01.y - c1.y; dz = f01.z - c1.z; dw = f01.w - c1.w;
        sq0 += dx * dx + dy * dy + dz * dz + dw * dw;
        dx = f10.x - c0.x; dy = f10.y - c0.y; dz = f10.z - c0.z; dw = f10.w - c0.w;
        float sq1 = dx * dx + dy * dy + dz * dz + dw * dw;
        dx = f11.x - c1.x; dy = f11.y - c1.y; dz = f11.z - c1.z; dw = f11.w - c1.w;
        sq1 += dx * dx + dy * dy + dz * dz + dw * dw;

#pragma unroll
        for (int m = 32; m >= 1; m >>= 1) {
            sq0 += __shfl_xor(sq0, m);
            sq1 += __shfl_xor(sq1, m);
        }
        if (lane == 0) {
            result[b0] = sq0;
            result[b1] = sq1;
        }
    }
    if (i < cnt) {
        const int b = ord[i];
        const float4 f0 = *reinterpret_cast<const float4*>(&features[b * DIM + d]);
        const float4 f1 = *reinterpret_cast<const float4*>(&features[b * DIM + d + 4]);
        sA.x += f0.x; sA.y += f0.y; sA.z += f0.z; sA.w += f0.w;
        sB.x += f1.x; sB.y += f1.y; sB.z += f1.z; sB.w += f1.w;
        float dx, dy, dz, dw;
        dx = f0.x - c0.x; dy = f0.y - c0.y; dz = f0.z - c0.z; dw = f0.w - c0.w;
        float sq = dx * dx + dy * dy + dz * dz + dw * dw;
        dx = f1.x - c1.x; dy = f1.y - c1.y; dz = f1.z - c1.z; dw = f1.w - c1.w;
        sq += dx * dx + dy * dy + dz * dz + dw * dw;
#pragma unroll
        for (int m = 32; m >= 1; m >>= 1) sq += __shfl_xor(sq, m);
        if (lane == 0) result[b] = sq;
    }

    // cross-wave reduction in LDS, then one streaming partial write per block
    float* r = &red[wave][d];
    r[0] = sA.x; r[1] = sA.y; r[2] = sA.z; r[3] = sA.w;
    r[4] = sB.x; r[5] = sB.y; r[6] = sB.z; r[7] = sB.w;
    __syncthreads();

    const int t = threadIdx.x;
    if (use_part) {
        float* dst = &aux[(blockIdx.x * NCLS + c) * DIM];
#pragma unroll
        for (int k = 0; k < DIM / CBLOCK; ++k) {
            const int dd = k * CBLOCK + t;
            dst[dd] = red[0][dd] + red[1][dd] + red[2][dd] + red[3][dd];
        }
    } else {
#pragma unroll
        for (int k = 0; k < DIM / CBLOCK; ++k) {
            const int dd = k * CBLOCK + t;
            const float s = red[0][dd] + red[1][dd] + red[2][dd] + red[3][dd];
            unsafeAtomicAdd(&aux[c * DIM + dd], s);
        }
    }
}

// ---------------------------------------------------------------------------
// Kernel C: new_centers = centers - ALPHA * (cnt*center - sumf) / (cnt + 1)
// float4-vectorized over dims (4 elems/thread; 32-chunk partial sum).
// ---------------------------------------------------------------------------
__global__ void finalize_kernel(const float* __restrict__ centers,
                                const float* __restrict__ aux,
                                const int* __restrict__ counts,
                                float* __restrict__ new_centers,
                                const int use_part) {
    const int i4 = blockIdx.x * blockDim.x + threadIdx.x;   // float4 index
    if (i4 >= NCLS * DIM / 4) return;
    const int idx = i4 * 4;
    f4v s = (f4v)(0.0f);
    if (use_part) {
#pragma unroll
        for (int k = 0; k < CHUNKS; ++k)
            s += *reinterpret_cast<const f4v*>(&aux[k * NCLS * DIM + idx]);
    } else {
        s = *reinterpret_cast<const f4v*>(&aux[idx]);
    }
    const int c = idx >> 9;                 // / DIM
    const float cntf = (float)counts[c];
    const f4v ctr = *reinterpret_cast<const f4v*>(&centers[idx]);
    const f4v delta = (cntf * ctr - s) / (cntf + 1.0f);
    *reinterpret_cast<f4v*>(&new_centers[idx]) = ctr - ALPHA * delta;
}

extern "C" void kernel_launch(void* const* d_in, const int* in_sizes, int n_in,
                              void* d_out, int out_size, void* d_ws, size_t ws_size,
                              hipStream_t stream) {
    const float* features = (const float*)d_in[0];   // [65536, 512]
    const float* onehot   = (const float*)d_in[1];   // [65536, 100]
    const float* centers  = (const float*)d_in[2];   // [100, 512]

    float* result      = (float*)d_out;              // [65536]
    float* new_centers = (float*)d_out + BATCH;      // [100*512]

    char* ws = (char*)d_ws;
    int*   counts = (int*)(ws + WS_COUNTS_OFF);      // 128 ints
    int*   order  = (int*)(ws + WS_ORDER_OFF);       // NCLS*CAP ints
    float* aux    = (float*)(ws + WS_AUX_OFF);       // part or sumf

    const int use_part = (ws_size >= (size_t)WS_AUX_OFF + WS_PART_BYTES) ? 1 : 0;

    hipMemsetAsync(counts, 0, 128 * sizeof(int), stream);
    if (!use_part)
        hipMemsetAsync(aux, 0, NCLS * DIM * sizeof(float), stream);

    sort_kernel<<<BATCH / SORT_RPB, SORT_THREADS, 0, stream>>>(onehot, counts, order);

    dim3 grid(CHUNKS, NCLS);
    delta_kernel<<<grid, CBLOCK, 0, stream>>>(features, centers, order, counts, aux, result, use_part);

    finalize_kernel<<<(NCLS * DIM / 4 + 255) / 256, 256, 0, stream>>>(centers, aux, counts, new_centers, use_part);
}